// Round 1
// baseline (4392.853 us; speedup 1.0000x reference)
//
#include <hip/hip_runtime.h>
#include <hip/hip_bf16.h>

// LSTM_Net round 11: per-wave sync planes, no aggregator, no WG barriers.
// Insight: consumer wave w only needs rows [16w,16w+16) of h, which are
// produced exclusively by producer waves with the SAME wave index w across
// all 96 cb blocks. The 4 wave-planes are independent sync domains and the
// WG has zero intra-WG data sharing (creg, ldsb[wave] are wave-local).
// New chain per step (was ~6 LLC hops + 2 barriers):
//   wave: h-store (sc1, 256B) -> own s_waitcnt vmcnt(0) -> 8 replica flag
//   stores (lanes 0..7, fire-and-forget) ... consumer wave scans 96 flags of
//   its own plane in replica (cb&7) directly (2 loads/lane + __all) -> k-loop.
// L1 reordered: wait f1>=t -> h2 half of k-loop -> wait f0>=s -> h1 half
// (hides half of L1 compute under the cross-layer wait).
// Everything else = r10 verbatim (packed rings, coalesced sc1 h stores, fast
// exp2 epilogue, heaters, x-part MFMA overlapped before the wait).

#define B_  64
#define T_  256
#define IN_ 64
#define H_  768
#define G_  3072   // 4*H
#define K0_ 832    // IN_ + H_
#define K1_ 1536   // 2*H_
#define NWG0 96
#define NWGC 192   // compute WGs
#define NWGT 256   // + 64 heaters
#define CB_  96
#define SLOT_ (CB_ * 64 * 8)   // ring slot elements = 49152

typedef __bf16 bf16_t;
typedef bf16_t bf16x8 __attribute__((ext_vector_type(8)));
typedef float  f32x4  __attribute__((ext_vector_type(4)));

__device__ __forceinline__ unsigned short f2bf(float f) {
    union { float f; unsigned u; } v; v.f = f;
    unsigned r = v.u + 0x7FFFu + ((v.u >> 16) & 1u);
    return (unsigned short)(r >> 16);
}
__device__ __forceinline__ float fast_sigm(float x) {
    float e = __builtin_amdgcn_exp2f(-1.44269504f * x);
    return __builtin_amdgcn_rcpf(1.0f + e);
}
__device__ __forceinline__ float fast_tanh(float x) {
    float e = __builtin_amdgcn_exp2f(2.88539008f * x);
    return (e - 1.0f) * __builtin_amdgcn_rcpf(e + 1.0f);
}
__device__ __forceinline__ void st_llc_u32(unsigned* p, unsigned v) {
    asm volatile("global_store_dword %0, %1, off sc1" :: "v"(p), "v"(v) : "memory");
}
#define MFMA16(a, b, c) __builtin_amdgcn_mfma_f32_16x16x32_bf16((a), (b), (c), 0, 0, 0)
#define AGENT_LD(p) __hip_atomic_load((p), __ATOMIC_RELAXED, __HIP_MEMORY_SCOPE_AGENT)

// Wave-level scan of 96 per-wave flags (this wave's plane, one replica).
// asm "" memory fence stops LICM from hoisting the subsequent (loop-invariant
// address) ring loads above the poll loop — the old WG barrier used to
// provide this ordering.
#define POLL_GE(base, e) do {                                          \
    for (;;) {                                                         \
        int _fa = AGENT_LD(&(base)[i1]);                               \
        int _fb = AGENT_LD(&(base)[i2]);                               \
        if (__all(_fa >= (e) && _fb >= (e))) break;                    \
        __builtin_amdgcn_s_sleep(1);                                   \
    }                                                                  \
    asm volatile("" ::: "memory");                                     \
} while (0)

// ctrs layout (ints): f0[rep<8][wave<4][128] at 0..4095 (epoch e: h1[e-1]
// stored by that (wave,cb) producer), f1 same at 4096..8191, done at 8192.

// ---------------- prep ----------------
__global__ __launch_bounds__(256) void prep_kernel(
    const float* __restrict__ x,
    const float* __restrict__ Wih0, const float* __restrict__ Whh0,
    const float* __restrict__ bih0, const float* __restrict__ bhh0,
    const float* __restrict__ Wih1, const float* __restrict__ Whh1,
    const float* __restrict__ bih1, const float* __restrict__ bhh1,
    unsigned short* __restrict__ xsT,    // [T][B][64]
    unsigned short* __restrict__ W0cat,  // [3072][832]
    unsigned short* __restrict__ W1cat,  // [3072][1536]
    float* __restrict__ bias0, float* __restrict__ bias1,
    int* __restrict__ ctrs)              // [16384]
{
    int i = blockIdx.x * blockDim.x + threadIdx.x;
    int stride = gridDim.x * blockDim.x;
    for (int j = i; j < B_ * T_ * IN_; j += stride) {
        int b = j >> 14;
        int t = (j >> 6) & (T_ - 1);
        int k = j & (IN_ - 1);
        xsT[(((size_t)t * B_) + b) * IN_ + k] = f2bf(x[j] * (1.0f / 1.5f));
    }
    for (int j = i; j < G_ * IN_; j += stride) {
        int r = j >> 6; int k = j & 63;
        W0cat[(size_t)r * K0_ + k] = f2bf(Wih0[j]);
    }
    for (int j = i; j < G_ * H_; j += stride) {
        int r = j / H_; int k = j - r * H_;
        W0cat[(size_t)r * K0_ + IN_ + k] = f2bf(Whh0[j]);
        W1cat[(size_t)r * K1_ + k]       = f2bf(Wih1[j]);
        W1cat[(size_t)r * K1_ + H_ + k]  = f2bf(Whh1[j]);
    }
    for (int j = i; j < G_; j += stride) {
        bias0[j] = bih0[j] + bhh0[j];
        bias1[j] = bih1[j] + bhh1[j];
    }
    for (int j = i; j < 16384; j += stride) ctrs[j] = 0;
}

// ---------------- persistent wavefront recurrence ----------------
__global__ __launch_bounds__(256) void lstm_persistent(
    const unsigned short* __restrict__ xsT,
    const unsigned short* __restrict__ W0cat,
    const unsigned short* __restrict__ W1cat,
    const float* __restrict__ bias0, const float* __restrict__ bias1,
    unsigned short* __restrict__ h1ring,  // [T][96][64][8]
    unsigned short* __restrict__ h2ring,  // [T][96][64][8]
    float* __restrict__ hf32,             // [B][H] fp32 (t = T-1)
    int* __restrict__ ctrs)
{
    __shared__ unsigned short ldsb[4][16][8];

    const int tid  = threadIdx.x;
    const int lane = tid & 63;
    const int wave = tid >> 6;
    const int wg   = blockIdx.x;

    int* f0   = &ctrs[0];
    int* f1   = &ctrs[4096];
    int* done = &ctrs[8192];

    // ---------- heater WGs: pin GFX clock; poll dedicated done line ---------
    if (wg >= NWGC) {
        float a = 1.0f + (float)tid * 1e-7f;
        const float bm = 1.0000001f, cm = 1e-9f;
        for (;;) {
            for (int i = 0; i < 2048; i++)
                a = __builtin_fmaf(a, bm, cm);
            asm volatile("" : "+v"(a));
            int d = 0;
            if (lane == 0) d = AGENT_LD(done);
            d = __builtin_amdgcn_readfirstlane(d);
            if (d != 0) break;
        }
        return;
    }

    const bool isL1 = (wg >= NWG0);
    const int cb   = isL1 ? (wg - NWG0) : wg;
    const int c0   = cb * 8;
    const int frow = lane & 15;
    const int q    = lane >> 4;
    const int kof  = q * 8;
    const int m0   = wave * 16;

    const int i1 = lane;               // flag scan indices: 0..63
    const int i2 = 64 + (lane & 31);   // 64..95
    int* s0a = &f0[(cb & 7) * 512 + wave * 128];   // my replica, my plane
    int* s1a = &f1[(cb & 7) * 512 + wave * 128];

    const unsigned short* Wc = isL1 ? W1cat : W0cat;
    const int Kc = isL1 ? K1_ : K0_;
    int q0 = frow >> 3, col0 = c0 + (frow & 7);
    const unsigned short* Bp0 = Wc + (size_t)(q0 * H_ + col0) * Kc + kof;       // gates i,f
    const unsigned short* Bp1 = Wc + (size_t)((2 + q0) * H_ + col0) * Kc + kof; // gates g,o

    const float* bias = isL1 ? bias1 : bias0;
    const bool lowhalf = (lane & 15) < 8;
    const int ecol = c0 + (lane & 7);
    float bi = 0.f, bff = 0.f, bg = 0.f, bo = 0.f;
    if (lowhalf) {
        bi  = bias[0 * H_ + ecol];
        bff = bias[1 * H_ + ecol];
        bg  = bias[2 * H_ + ecol];
        bo  = bias[3 * H_ + ecol];
    }
    float creg[4] = {0.f, 0.f, 0.f, 0.f};

    const size_t aoff = (size_t)q * 512 + (size_t)(m0 + frow) * 8;
    const size_t stoff_e = (size_t)cb * 512 + (size_t)(m0 + (lane >> 2)) * 8
                         + (size_t)(lane & 3) * 2;

    if (!isL1) {
        // ------------- layer 0: superstep s computes t = s ------------------
        for (int s = 0; s < T_; ++s) {
            f32x4 acc0 = {0.f, 0.f, 0.f, 0.f};
            f32x4 acc1 = {0.f, 0.f, 0.f, 0.f};
            {
                const unsigned short* xsp =
                    xsT + ((size_t)s * B_ + m0 + frow) * IN_ + kof;
                #pragma unroll
                for (int ki = 0; ki < 2; ki++) {
                    bf16x8 a  = *(const bf16x8*)(xsp + ki * 32);
                    bf16x8 b0 = *(const bf16x8*)(Bp0 + ki * 32);
                    bf16x8 b1 = *(const bf16x8*)(Bp1 + ki * 32);
                    acc0 = MFMA16(a, b0, acc0);
                    acc1 = MFMA16(a, b1, acc1);
                }
            }
            if (s > 0) {
                POLL_GE(s0a, s);   // h1[s-1] of my plane fully published
                const unsigned short* hr = h1ring + (size_t)(s - 1) * SLOT_ + aoff;
                #pragma unroll
                for (int kj = 0; kj < 24; kj++) {
                    bf16x8 a  = *(const bf16x8*)(hr + kj * 2048);
                    bf16x8 b0 = *(const bf16x8*)(Bp0 + (kj + 2) * 32);
                    bf16x8 b1 = *(const bf16x8*)(Bp1 + (kj + 2) * 32);
                    acc0 = MFMA16(a, b0, acc0);
                    acc1 = MFMA16(a, b1, acc1);
                }
            }
            f32x4 pacc0, pacc1;
            #pragma unroll
            for (int j = 0; j < 4; j++) {
                pacc0[j] = __shfl_xor(acc0[j], 8);
                pacc1[j] = __shfl_xor(acc1[j], 8);
            }
            if (lowhalf) {
                #pragma unroll
                for (int j = 0; j < 4; j++) {
                    float pi = acc0[j]  + bi;
                    float pf = pacc0[j] + bff;
                    float pg = acc1[j]  + bg;
                    float po = pacc1[j] + bo;
                    float cn = fast_sigm(pf) * creg[j] + fast_sigm(pi) * fast_tanh(pg);
                    float hn = fast_sigm(po) * fast_tanh(cn);
                    creg[j] = cn;
                    ldsb[wave][q * 4 + j][lane & 7] = f2bf(hn);
                }
            }
            unsigned v = ((const unsigned*)&ldsb[wave][0][0])[lane];
            st_llc_u32((unsigned*)(h1ring + (size_t)s * SLOT_ + stoff_e), v);
            asm volatile("s_waitcnt vmcnt(0)" ::: "memory");   // my h at LLC
            if (lane < 8)   // publish epoch s+1 to all 8 replicas, my plane
                st_llc_u32((unsigned*)&f0[lane * 512 + wave * 128 + cb],
                           (unsigned)(s + 1));
        }
    } else {
        // ------------- layer 1: superstep s computes t = s - 1 --------------
        for (int s = 1; s <= T_; ++s) {
            const int t = s - 1;
            f32x4 acc0 = {0.f, 0.f, 0.f, 0.f};
            f32x4 acc1 = {0.f, 0.f, 0.f, 0.f};
            if (t > 0) {
                POLL_GE(s1a, t);   // h2[t-1] ready (own layer, arrives early)
                const unsigned short* h2r = h2ring + (size_t)(t - 1) * SLOT_ + aoff;
                #pragma unroll
                for (int ki = 0; ki < 24; ki++) {
                    bf16x8 a  = *(const bf16x8*)(h2r + ki * 2048);
                    bf16x8 b0 = *(const bf16x8*)(Bp0 + (ki + 24) * 32);
                    bf16x8 b1 = *(const bf16x8*)(Bp1 + (ki + 24) * 32);
                    acc0 = MFMA16(a, b0, acc0);
                    acc1 = MFMA16(a, b1, acc1);
                }
            }
            POLL_GE(s0a, s);       // h1[t] ready (cross-layer)
            {
                const unsigned short* h1r = h1ring + (size_t)t * SLOT_ + aoff;
                #pragma unroll
                for (int ki = 0; ki < 24; ki++) {
                    bf16x8 a  = *(const bf16x8*)(h1r + ki * 2048);
                    bf16x8 b0 = *(const bf16x8*)(Bp0 + ki * 32);
                    bf16x8 b1 = *(const bf16x8*)(Bp1 + ki * 32);
                    acc0 = MFMA16(a, b0, acc0);
                    acc1 = MFMA16(a, b1, acc1);
                }
            }
            f32x4 pacc0, pacc1;
            #pragma unroll
            for (int j = 0; j < 4; j++) {
                pacc0[j] = __shfl_xor(acc0[j], 8);
                pacc1[j] = __shfl_xor(acc1[j], 8);
            }
            if (lowhalf) {
                #pragma unroll
                for (int j = 0; j < 4; j++) {
                    int row = m0 + q * 4 + j;
                    float pi = acc0[j]  + bi;
                    float pf = pacc0[j] + bff;
                    float pg = acc1[j]  + bg;
                    float po = pacc1[j] + bo;
                    float cn = fast_sigm(pf) * creg[j] + fast_sigm(pi) * fast_tanh(pg);
                    float hn = fast_sigm(po) * fast_tanh(cn);
                    creg[j] = cn;
                    ldsb[wave][q * 4 + j][lane & 7] = f2bf(hn);
                    if (t == T_ - 1) hf32[(size_t)row * H_ + ecol] = hn;
                }
            }
            unsigned v = ((const unsigned*)&ldsb[wave][0][0])[lane];
            st_llc_u32((unsigned*)(h2ring + (size_t)t * SLOT_ + stoff_e), v);
            asm volatile("s_waitcnt vmcnt(0)" ::: "memory");
            if (lane < 8)
                st_llc_u32((unsigned*)&f1[lane * 512 + wave * 128 + cb],
                           (unsigned)s);
        }
        if (wg == NWG0 && tid == 0) st_llc_u32((unsigned*)done, 1u);
    }
}

// ---------------- head ----------------
__global__ __launch_bounds__(256) void head_kernel(
    const float* __restrict__ hlast,
    const float* __restrict__ W1, const float* __restrict__ b1,
    const float* __restrict__ W2, const float* __restrict__ b2,
    float* __restrict__ out)
{
    __shared__ float hs[H_];
    __shared__ float partial[4];
    int b = blockIdx.x;
    int tid = threadIdx.x;
    for (int j = tid; j < H_; j += 256) hs[j] = hlast[(size_t)b * H_ + j];
    __syncthreads();
    float z = 0.f;
    const float* w = W1 + (size_t)tid * H_;
    for (int j = 0; j < H_; j++) z += hs[j] * w[j];
    z += b1[tid];
    z = z / (1.0f + fabsf(z));
    float p = z * W2[tid];
    #pragma unroll
    for (int off = 32; off > 0; off >>= 1) p += __shfl_down(p, off, 64);
    if ((tid & 63) == 0) partial[tid >> 6] = p;
    __syncthreads();
    if (tid == 0) {
        float s = partial[0] + partial[1] + partial[2] + partial[3];
        out[b] = (s + b2[0]) * 70.0f;
    }
}

extern "C" void kernel_launch(void* const* d_in, const int* in_sizes, int n_in,
                              void* d_out, int out_size, void* d_ws, size_t ws_size,
                              hipStream_t stream) {
    const float* x    = (const float*)d_in[0];
    const float* Wih0 = (const float*)d_in[1];
    const float* Whh0 = (const float*)d_in[2];
    const float* bih0 = (const float*)d_in[3];
    const float* bhh0 = (const float*)d_in[4];
    const float* Wih1 = (const float*)d_in[5];
    const float* Whh1 = (const float*)d_in[6];
    const float* bih1 = (const float*)d_in[7];
    const float* bhh1 = (const float*)d_in[8];
    const float* W1   = (const float*)d_in[9];
    const float* b1   = (const float*)d_in[10];
    const float* W2   = (const float*)d_in[11];
    const float* b2   = (const float*)d_in[12];
    float* out = (float*)d_out;

    char* w = (char*)d_ws;
    int* ctrs = (int*)w;                          w += 65536;
    unsigned short* h1ring = (unsigned short*)w;  w += (size_t)T_ * SLOT_ * 2;
    unsigned short* h2ring = (unsigned short*)w;  w += (size_t)T_ * SLOT_ * 2;
    unsigned short* xsT    = (unsigned short*)w;  w += (size_t)B_ * T_ * IN_ * 2;
    unsigned short* W0cat  = (unsigned short*)w;  w += (size_t)G_ * K0_ * 2;
    unsigned short* W1cat  = (unsigned short*)w;  w += (size_t)G_ * K1_ * 2;
    float* bias0 = (float*)w;                     w += G_ * 4;
    float* bias1 = (float*)w;                     w += G_ * 4;
    float* hf32  = (float*)w;                     w += (size_t)B_ * H_ * 4;

    prep_kernel<<<1024, 256, 0, stream>>>(x, Wih0, Whh0, bih0, bhh0,
                                          Wih1, Whh1, bih1, bhh1,
                                          xsT, W0cat, W1cat, bias0, bias1, ctrs);
    lstm_persistent<<<NWGT, 256, 0, stream>>>(xsT, W0cat, W1cat, bias0, bias1,
                                              h1ring, h2ring, hf32, ctrs);
    head_kernel<<<B_, 256, 0, stream>>>(hf32, W1, b1, W2, b2, out);
}

// Round 2
// 3195.762 us; speedup vs baseline: 1.3746x; 1.3746x over previous
//
#include <hip/hip_runtime.h>
#include <hip/hip_bf16.h>

// LSTM_Net round 12: r10 skeleton + direct consumer flag scan (no aggregator).
// r11 post-mortem: per-wave sync broke codegen (VGPR 128->44, k-loop pipeline
// lost) and multiplied flag traffic 32x (WRITE_SIZE 2x, 46ms outliers).
// r12 keeps r10's WG-level structure verbatim -- guarded poll in ONE wave,
// __syncthreads release, clean unrolled k-loops, coalesced sc1 h stores,
// drain barrier, heaters -- and removes only the aggregator hop:
//   producers: after drain barrier, wave0 lanes 0..7 store epoch to 8
//     replicated flag arrays (8 stores/WG/step, ~= r10's 1+8)
//   consumers: wave0 scans the 96 flags of replica (cb&7) directly
//     (2 loads/lane + __all), wave1 scans f1 for L1; then __syncthreads.
// Chain loses 2 LLC hops (aggregator detect + replica publish).

#define B_  64
#define T_  256
#define IN_ 64
#define H_  768
#define G_  3072   // 4*H
#define K0_ 832    // IN_ + H_
#define K1_ 1536   // 2*H_
#define NWG0 96
#define NWGC 192   // compute WGs
#define NWGT 256   // + 64 heaters
#define CB_  96
#define SLOT_ (CB_ * 64 * 8)   // ring slot elements = 49152

typedef __bf16 bf16_t;
typedef bf16_t bf16x8 __attribute__((ext_vector_type(8)));
typedef float  f32x4  __attribute__((ext_vector_type(4)));

__device__ __forceinline__ unsigned short f2bf(float f) {
    union { float f; unsigned u; } v; v.f = f;
    unsigned r = v.u + 0x7FFFu + ((v.u >> 16) & 1u);
    return (unsigned short)(r >> 16);
}
__device__ __forceinline__ float fast_sigm(float x) {
    float e = __builtin_amdgcn_exp2f(-1.44269504f * x);
    return __builtin_amdgcn_rcpf(1.0f + e);
}
__device__ __forceinline__ float fast_tanh(float x) {
    float e = __builtin_amdgcn_exp2f(2.88539008f * x);
    return (e - 1.0f) * __builtin_amdgcn_rcpf(e + 1.0f);
}
__device__ __forceinline__ void st_llc_u32(unsigned* p, unsigned v) {
    asm volatile("global_store_dword %0, %1, off sc1" :: "v"(p), "v"(v) : "memory");
}
#define MFMA16(a, b, c) __builtin_amdgcn_mfma_f32_16x16x32_bf16((a), (b), (c), 0, 0, 0)
#define AGENT_LD(p) __hip_atomic_load((p), __ATOMIC_RELAXED, __HIP_MEMORY_SCOPE_AGENT)

// ctrs layout (ints): f0[rep<8][128] at 0..1023 (flag value e: that WG's
// h1[e-1] is stored & drained), f1 same at 1024..2047, done at 2048.

// ---------------- prep ----------------
__global__ __launch_bounds__(256) void prep_kernel(
    const float* __restrict__ x,
    const float* __restrict__ Wih0, const float* __restrict__ Whh0,
    const float* __restrict__ bih0, const float* __restrict__ bhh0,
    const float* __restrict__ Wih1, const float* __restrict__ Whh1,
    const float* __restrict__ bih1, const float* __restrict__ bhh1,
    unsigned short* __restrict__ xsT,    // [T][B][64]
    unsigned short* __restrict__ W0cat,  // [3072][832]
    unsigned short* __restrict__ W1cat,  // [3072][1536]
    float* __restrict__ bias0, float* __restrict__ bias1,
    int* __restrict__ ctrs)              // [16384]
{
    int i = blockIdx.x * blockDim.x + threadIdx.x;
    int stride = gridDim.x * blockDim.x;
    for (int j = i; j < B_ * T_ * IN_; j += stride) {
        int b = j >> 14;
        int t = (j >> 6) & (T_ - 1);
        int k = j & (IN_ - 1);
        xsT[(((size_t)t * B_) + b) * IN_ + k] = f2bf(x[j] * (1.0f / 1.5f));
    }
    for (int j = i; j < G_ * IN_; j += stride) {
        int r = j >> 6; int k = j & 63;
        W0cat[(size_t)r * K0_ + k] = f2bf(Wih0[j]);
    }
    for (int j = i; j < G_ * H_; j += stride) {
        int r = j / H_; int k = j - r * H_;
        W0cat[(size_t)r * K0_ + IN_ + k] = f2bf(Whh0[j]);
        W1cat[(size_t)r * K1_ + k]       = f2bf(Wih1[j]);
        W1cat[(size_t)r * K1_ + H_ + k]  = f2bf(Whh1[j]);
    }
    for (int j = i; j < G_; j += stride) {
        bias0[j] = bih0[j] + bhh0[j];
        bias1[j] = bih1[j] + bhh1[j];
    }
    for (int j = i; j < 16384; j += stride) ctrs[j] = 0;
}

// ---------------- persistent wavefront recurrence ----------------
__global__ __launch_bounds__(256) void lstm_persistent(
    const unsigned short* __restrict__ xsT,
    const unsigned short* __restrict__ W0cat,
    const unsigned short* __restrict__ W1cat,
    const float* __restrict__ bias0, const float* __restrict__ bias1,
    unsigned short* __restrict__ h1ring,  // [T][96][64][8]
    unsigned short* __restrict__ h2ring,  // [T][96][64][8]
    float* __restrict__ hf32,             // [B][H] fp32 (t = T-1)
    int* __restrict__ ctrs)
{
    __shared__ unsigned short ldsb[4][16][8];

    const int tid  = threadIdx.x;
    const int lane = tid & 63;
    const int wave = tid >> 6;
    const int wg   = blockIdx.x;

    int* f0   = &ctrs[0];
    int* f1   = &ctrs[1024];
    int* done = &ctrs[2048];

    // ---------- heater WGs: pin GFX clock; poll dedicated done line ---------
    if (wg >= NWGC) {
        float a = 1.0f + (float)tid * 1e-7f;
        const float bm = 1.0000001f, cm = 1e-9f;
        for (;;) {
            for (int i = 0; i < 2048; i++)
                a = __builtin_fmaf(a, bm, cm);
            asm volatile("" : "+v"(a));
            int d = 0;
            if (lane == 0) d = AGENT_LD(done);
            d = __builtin_amdgcn_readfirstlane(d);
            if (d != 0) break;
        }
        return;
    }

    const bool isL1 = (wg >= NWG0);
    const int cb   = isL1 ? (wg - NWG0) : wg;
    const int c0   = cb * 8;
    const int frow = lane & 15;
    const int q    = lane >> 4;
    const int kof  = q * 8;
    const int m0   = wave * 16;

    const int i1 = lane;               // flag scan indices: 0..63
    const int i2 = 64 + (lane & 31);   // 64..95
    int* rep0 = &f0[(cb & 7) * 128];   // my replica of the 96 L0 flags
    int* rep1 = &f1[(cb & 7) * 128];

    const unsigned short* Wc = isL1 ? W1cat : W0cat;
    const int Kc = isL1 ? K1_ : K0_;
    int q0 = frow >> 3, col0 = c0 + (frow & 7);
    const unsigned short* Bp0 = Wc + (size_t)(q0 * H_ + col0) * Kc + kof;       // gates i,f
    const unsigned short* Bp1 = Wc + (size_t)((2 + q0) * H_ + col0) * Kc + kof; // gates g,o

    const float* bias = isL1 ? bias1 : bias0;
    const bool lowhalf = (lane & 15) < 8;
    const int ecol = c0 + (lane & 7);
    float bi = 0.f, bff = 0.f, bg = 0.f, bo = 0.f;
    if (lowhalf) {
        bi  = bias[0 * H_ + ecol];
        bff = bias[1 * H_ + ecol];
        bg  = bias[2 * H_ + ecol];
        bo  = bias[3 * H_ + ecol];
    }
    float creg[4] = {0.f, 0.f, 0.f, 0.f};

    const size_t aoff = (size_t)q * 512 + (size_t)(m0 + frow) * 8;
    const size_t stoff_e = (size_t)cb * 512 + (size_t)(m0 + (lane >> 2)) * 8
                         + (size_t)(lane & 3) * 2;

    if (!isL1) {
        // ------------- layer 0: superstep s computes t = s ------------------
        for (int s = 0; s < T_; ++s) {
            f32x4 acc0 = {0.f, 0.f, 0.f, 0.f};
            f32x4 acc1 = {0.f, 0.f, 0.f, 0.f};
            {
                const unsigned short* xsp =
                    xsT + ((size_t)s * B_ + m0 + frow) * IN_ + kof;
                #pragma unroll
                for (int ki = 0; ki < 2; ki++) {
                    bf16x8 a  = *(const bf16x8*)(xsp + ki * 32);
                    bf16x8 b0 = *(const bf16x8*)(Bp0 + ki * 32);
                    bf16x8 b1 = *(const bf16x8*)(Bp1 + ki * 32);
                    acc0 = MFMA16(a, b0, acc0);
                    acc1 = MFMA16(a, b1, acc1);
                }
            }
            if (s > 0) {
                if (wave == 0) {   // scan all 96 producer flags directly
                    for (;;) {
                        int fa = AGENT_LD(&rep0[i1]);
                        int fb = AGENT_LD(&rep0[i2]);
                        if (__all(fa >= s && fb >= s)) break;
                        __builtin_amdgcn_s_sleep(1);
                    }
                }
                __syncthreads();
                const unsigned short* hr = h1ring + (size_t)(s - 1) * SLOT_ + aoff;
                #pragma unroll
                for (int kj = 0; kj < 24; kj++) {
                    bf16x8 a  = *(const bf16x8*)(hr + kj * 2048);
                    bf16x8 b0 = *(const bf16x8*)(Bp0 + (kj + 2) * 32);
                    bf16x8 b1 = *(const bf16x8*)(Bp1 + (kj + 2) * 32);
                    acc0 = MFMA16(a, b0, acc0);
                    acc1 = MFMA16(a, b1, acc1);
                }
            }
            f32x4 pacc0, pacc1;
            #pragma unroll
            for (int j = 0; j < 4; j++) {
                pacc0[j] = __shfl_xor(acc0[j], 8);
                pacc1[j] = __shfl_xor(acc1[j], 8);
            }
            if (lowhalf) {
                #pragma unroll
                for (int j = 0; j < 4; j++) {
                    float pi = acc0[j]  + bi;
                    float pf = pacc0[j] + bff;
                    float pg = acc1[j]  + bg;
                    float po = pacc1[j] + bo;
                    float cn = fast_sigm(pf) * creg[j] + fast_sigm(pi) * fast_tanh(pg);
                    float hn = fast_sigm(po) * fast_tanh(cn);
                    creg[j] = cn;
                    ldsb[wave][q * 4 + j][lane & 7] = f2bf(hn);
                }
            }
            unsigned v = ((const unsigned*)&ldsb[wave][0][0])[lane];
            st_llc_u32((unsigned*)(h1ring + (size_t)s * SLOT_ + stoff_e), v);
            asm volatile("s_waitcnt vmcnt(0)" ::: "memory");
            __syncthreads();   // all 4 waves' h stores drained
            if (wave == 0 && lane < 8)   // publish epoch s+1 to 8 replicas
                st_llc_u32((unsigned*)&f0[lane * 128 + cb], (unsigned)(s + 1));
        }
    } else {
        // ------------- layer 1: superstep s computes t = s - 1 --------------
        for (int s = 1; s <= T_; ++s) {
            const int t = s - 1;
            if (wave == 0) {   // h1[t] ready when all f0 >= t+1 = s
                for (;;) {
                    int fa = AGENT_LD(&rep0[i1]);
                    int fb = AGENT_LD(&rep0[i2]);
                    if (__all(fa >= s && fb >= s)) break;
                    __builtin_amdgcn_s_sleep(1);
                }
            }
            if (wave == 1 && t > 0) {   // h2[t-1] ready when all f1 >= t
                for (;;) {
                    int fa = AGENT_LD(&rep1[i1]);
                    int fb = AGENT_LD(&rep1[i2]);
                    if (__all(fa >= t && fb >= t)) break;
                    __builtin_amdgcn_s_sleep(1);
                }
            }
            __syncthreads();
            f32x4 acc0 = {0.f, 0.f, 0.f, 0.f};
            f32x4 acc1 = {0.f, 0.f, 0.f, 0.f};
            const unsigned short* h1r = h1ring + (size_t)t * SLOT_ + aoff;
            #pragma unroll
            for (int ki = 0; ki < 24; ki++) {
                bf16x8 a  = *(const bf16x8*)(h1r + ki * 2048);
                bf16x8 b0 = *(const bf16x8*)(Bp0 + ki * 32);
                bf16x8 b1 = *(const bf16x8*)(Bp1 + ki * 32);
                acc0 = MFMA16(a, b0, acc0);
                acc1 = MFMA16(a, b1, acc1);
            }
            if (t > 0) {
                const unsigned short* h2r = h2ring + (size_t)(t - 1) * SLOT_ + aoff;
                #pragma unroll
                for (int ki = 0; ki < 24; ki++) {
                    bf16x8 a  = *(const bf16x8*)(h2r + ki * 2048);
                    bf16x8 b0 = *(const bf16x8*)(Bp0 + (ki + 24) * 32);
                    bf16x8 b1 = *(const bf16x8*)(Bp1 + (ki + 24) * 32);
                    acc0 = MFMA16(a, b0, acc0);
                    acc1 = MFMA16(a, b1, acc1);
                }
            }
            f32x4 pacc0, pacc1;
            #pragma unroll
            for (int j = 0; j < 4; j++) {
                pacc0[j] = __shfl_xor(acc0[j], 8);
                pacc1[j] = __shfl_xor(acc1[j], 8);
            }
            if (lowhalf) {
                #pragma unroll
                for (int j = 0; j < 4; j++) {
                    int row = m0 + q * 4 + j;
                    float pi = acc0[j]  + bi;
                    float pf = pacc0[j] + bff;
                    float pg = acc1[j]  + bg;
                    float po = pacc1[j] + bo;
                    float cn = fast_sigm(pf) * creg[j] + fast_sigm(pi) * fast_tanh(pg);
                    float hn = fast_sigm(po) * fast_tanh(cn);
                    creg[j] = cn;
                    ldsb[wave][q * 4 + j][lane & 7] = f2bf(hn);
                    if (t == T_ - 1) hf32[(size_t)row * H_ + ecol] = hn;
                }
            }
            unsigned v = ((const unsigned*)&ldsb[wave][0][0])[lane];
            st_llc_u32((unsigned*)(h2ring + (size_t)t * SLOT_ + stoff_e), v);
            asm volatile("s_waitcnt vmcnt(0)" ::: "memory");
            __syncthreads();
            if (wave == 0 && lane < 8)
                st_llc_u32((unsigned*)&f1[lane * 128 + cb], (unsigned)s);
        }
        if (wg == NWG0 && tid == 0) st_llc_u32((unsigned*)done, 1u);
    }
}

// ---------------- head ----------------
__global__ __launch_bounds__(256) void head_kernel(
    const float* __restrict__ hlast,
    const float* __restrict__ W1, const float* __restrict__ b1,
    const float* __restrict__ W2, const float* __restrict__ b2,
    float* __restrict__ out)
{
    __shared__ float hs[H_];
    __shared__ float partial[4];
    int b = blockIdx.x;
    int tid = threadIdx.x;
    for (int j = tid; j < H_; j += 256) hs[j] = hlast[(size_t)b * H_ + j];
    __syncthreads();
    float z = 0.f;
    const float* w = W1 + (size_t)tid * H_;
    for (int j = 0; j < H_; j++) z += hs[j] * w[j];
    z += b1[tid];
    z = z / (1.0f + fabsf(z));
    float p = z * W2[tid];
    #pragma unroll
    for (int off = 32; off > 0; off >>= 1) p += __shfl_down(p, off, 64);
    if ((tid & 63) == 0) partial[tid >> 6] = p;
    __syncthreads();
    if (tid == 0) {
        float s = partial[0] + partial[1] + partial[2] + partial[3];
        out[b] = (s + b2[0]) * 70.0f;
    }
}

extern "C" void kernel_launch(void* const* d_in, const int* in_sizes, int n_in,
                              void* d_out, int out_size, void* d_ws, size_t ws_size,
                              hipStream_t stream) {
    const float* x    = (const float*)d_in[0];
    const float* Wih0 = (const float*)d_in[1];
    const float* Whh0 = (const float*)d_in[2];
    const float* bih0 = (const float*)d_in[3];
    const float* bhh0 = (const float*)d_in[4];
    const float* Wih1 = (const float*)d_in[5];
    const float* Whh1 = (const float*)d_in[6];
    const float* bih1 = (const float*)d_in[7];
    const float* bhh1 = (const float*)d_in[8];
    const float* W1   = (const float*)d_in[9];
    const float* b1   = (const float*)d_in[10];
    const float* W2   = (const float*)d_in[11];
    const float* b2   = (const float*)d_in[12];
    float* out = (float*)d_out;

    char* w = (char*)d_ws;
    int* ctrs = (int*)w;                          w += 65536;
    unsigned short* h1ring = (unsigned short*)w;  w += (size_t)T_ * SLOT_ * 2;
    unsigned short* h2ring = (unsigned short*)w;  w += (size_t)T_ * SLOT_ * 2;
    unsigned short* xsT    = (unsigned short*)w;  w += (size_t)B_ * T_ * IN_ * 2;
    unsigned short* W0cat  = (unsigned short*)w;  w += (size_t)G_ * K0_ * 2;
    unsigned short* W1cat  = (unsigned short*)w;  w += (size_t)G_ * K1_ * 2;
    float* bias0 = (float*)w;                     w += G_ * 4;
    float* bias1 = (float*)w;                     w += G_ * 4;
    float* hf32  = (float*)w;                     w += (size_t)B_ * H_ * 4;

    prep_kernel<<<1024, 256, 0, stream>>>(x, Wih0, Whh0, bih0, bhh0,
                                          Wih1, Whh1, bih1, bhh1,
                                          xsT, W0cat, W1cat, bias0, bias1, ctrs);
    lstm_persistent<<<NWGT, 256, 0, stream>>>(xsT, W0cat, W1cat, bias0, bias1,
                                              h1ring, h2ring, hf32, ctrs);
    head_kernel<<<B_, 256, 0, stream>>>(hf32, W1, b1, W2, b2, out);
}

// Round 3
// 2507.167 us; speedup vs baseline: 1.7521x; 1.2747x over previous
//
#include <hip/hip_runtime.h>
#include <hip/hip_bf16.h>

// LSTM_Net round 13: full-MLP k-loop + register-resident weights.
// r12 post-mortem: removing the aggregator (2 LLC hops) was NEUTRAL -> the
// flag chain is not the floor. Counters say VGPR=132 at 1 WG/CU: the k-loop
// (24-48 LLC loads/lane/step) runs at MLP~10, i.e. 3-5 serialized LLC
// latency rounds per step, with zero TLP to hide it. Fix:
//   __launch_bounds__(256,1) -> 512 VGPR budget at the SAME occupancy
//   (we already run 1 wave/SIMD).
//   - B-fragments (weights) are step-invariant: preload into registers
//     once (L0: 52 frags; L1: h1-part 48 frags; h2-part streamed from L2).
//   - A-fragments loaded as fully-unrolled SSA arrays: all 24/48 LLC loads
//     in flight -> 1 latency round.
// Sync scheme/stores/flags/heaters = r12 verbatim.

#define B_  64
#define T_  256
#define IN_ 64
#define H_  768
#define G_  3072   // 4*H
#define K0_ 832    // IN_ + H_
#define K1_ 1536   // 2*H_
#define NWG0 96
#define NWGC 192   // compute WGs
#define NWGT 256   // + 64 heaters
#define CB_  96
#define SLOT_ (CB_ * 64 * 8)   // ring slot elements = 49152

typedef __bf16 bf16_t;
typedef bf16_t bf16x8 __attribute__((ext_vector_type(8)));
typedef float  f32x4  __attribute__((ext_vector_type(4)));

__device__ __forceinline__ unsigned short f2bf(float f) {
    union { float f; unsigned u; } v; v.f = f;
    unsigned r = v.u + 0x7FFFu + ((v.u >> 16) & 1u);
    return (unsigned short)(r >> 16);
}
__device__ __forceinline__ float fast_sigm(float x) {
    float e = __builtin_amdgcn_exp2f(-1.44269504f * x);
    return __builtin_amdgcn_rcpf(1.0f + e);
}
__device__ __forceinline__ float fast_tanh(float x) {
    float e = __builtin_amdgcn_exp2f(2.88539008f * x);
    return (e - 1.0f) * __builtin_amdgcn_rcpf(e + 1.0f);
}
__device__ __forceinline__ void st_llc_u32(unsigned* p, unsigned v) {
    asm volatile("global_store_dword %0, %1, off sc1" :: "v"(p), "v"(v) : "memory");
}
#define MFMA16(a, b, c) __builtin_amdgcn_mfma_f32_16x16x32_bf16((a), (b), (c), 0, 0, 0)
#define AGENT_LD(p) __hip_atomic_load((p), __ATOMIC_RELAXED, __HIP_MEMORY_SCOPE_AGENT)

// ctrs layout (ints): f0[rep<8][128] at 0..1023 (flag value e: that WG's
// h1[e-1] is stored & drained), f1 same at 1024..2047, done at 2048.

// ---------------- prep ----------------
__global__ __launch_bounds__(256) void prep_kernel(
    const float* __restrict__ x,
    const float* __restrict__ Wih0, const float* __restrict__ Whh0,
    const float* __restrict__ bih0, const float* __restrict__ bhh0,
    const float* __restrict__ Wih1, const float* __restrict__ Whh1,
    const float* __restrict__ bih1, const float* __restrict__ bhh1,
    unsigned short* __restrict__ xsT,    // [T][B][64]
    unsigned short* __restrict__ W0cat,  // [3072][832]
    unsigned short* __restrict__ W1cat,  // [3072][1536]
    float* __restrict__ bias0, float* __restrict__ bias1,
    int* __restrict__ ctrs)              // [16384]
{
    int i = blockIdx.x * blockDim.x + threadIdx.x;
    int stride = gridDim.x * blockDim.x;
    for (int j = i; j < B_ * T_ * IN_; j += stride) {
        int b = j >> 14;
        int t = (j >> 6) & (T_ - 1);
        int k = j & (IN_ - 1);
        xsT[(((size_t)t * B_) + b) * IN_ + k] = f2bf(x[j] * (1.0f / 1.5f));
    }
    for (int j = i; j < G_ * IN_; j += stride) {
        int r = j >> 6; int k = j & 63;
        W0cat[(size_t)r * K0_ + k] = f2bf(Wih0[j]);
    }
    for (int j = i; j < G_ * H_; j += stride) {
        int r = j / H_; int k = j - r * H_;
        W0cat[(size_t)r * K0_ + IN_ + k] = f2bf(Whh0[j]);
        W1cat[(size_t)r * K1_ + k]       = f2bf(Wih1[j]);
        W1cat[(size_t)r * K1_ + H_ + k]  = f2bf(Whh1[j]);
    }
    for (int j = i; j < G_; j += stride) {
        bias0[j] = bih0[j] + bhh0[j];
        bias1[j] = bih1[j] + bhh1[j];
    }
    for (int j = i; j < 16384; j += stride) ctrs[j] = 0;
}

// ---------------- persistent wavefront recurrence ----------------
__global__ __launch_bounds__(256, 1) void lstm_persistent(
    const unsigned short* __restrict__ xsT,
    const unsigned short* __restrict__ W0cat,
    const unsigned short* __restrict__ W1cat,
    const float* __restrict__ bias0, const float* __restrict__ bias1,
    unsigned short* __restrict__ h1ring,  // [T][96][64][8]
    unsigned short* __restrict__ h2ring,  // [T][96][64][8]
    float* __restrict__ hf32,             // [B][H] fp32 (t = T-1)
    int* __restrict__ ctrs)
{
    __shared__ unsigned short ldsb[4][16][8];

    const int tid  = threadIdx.x;
    const int lane = tid & 63;
    const int wave = tid >> 6;
    const int wg   = blockIdx.x;

    int* f0   = &ctrs[0];
    int* f1   = &ctrs[1024];
    int* done = &ctrs[2048];

    // ---------- heater WGs: pin GFX clock; poll dedicated done line ---------
    if (wg >= NWGC) {
        float a = 1.0f + (float)tid * 1e-7f;
        const float bm = 1.0000001f, cm = 1e-9f;
        for (;;) {
            for (int i = 0; i < 2048; i++)
                a = __builtin_fmaf(a, bm, cm);
            asm volatile("" : "+v"(a));
            int d = 0;
            if (lane == 0) d = AGENT_LD(done);
            d = __builtin_amdgcn_readfirstlane(d);
            if (d != 0) break;
        }
        return;
    }

    const bool isL1 = (wg >= NWG0);
    const int cb   = isL1 ? (wg - NWG0) : wg;
    const int c0   = cb * 8;
    const int frow = lane & 15;
    const int q    = lane >> 4;
    const int kof  = q * 8;
    const int m0   = wave * 16;

    const int i1 = lane;               // flag scan indices: 0..63
    const int i2 = 64 + (lane & 31);   // 64..95
    int* rep0 = &f0[(cb & 7) * 128];   // my replica of the 96 L0 flags
    int* rep1 = &f1[(cb & 7) * 128];

    const unsigned short* Wc = isL1 ? W1cat : W0cat;
    const int Kc = isL1 ? K1_ : K0_;
    int q0 = frow >> 3, col0 = c0 + (frow & 7);
    const unsigned short* Bp0 = Wc + (size_t)(q0 * H_ + col0) * Kc + kof;       // gates i,f
    const unsigned short* Bp1 = Wc + (size_t)((2 + q0) * H_ + col0) * Kc + kof; // gates g,o

    const float* bias = isL1 ? bias1 : bias0;
    const bool lowhalf = (lane & 15) < 8;
    const int ecol = c0 + (lane & 7);
    float bi = 0.f, bff = 0.f, bg = 0.f, bo = 0.f;
    if (lowhalf) {
        bi  = bias[0 * H_ + ecol];
        bff = bias[1 * H_ + ecol];
        bg  = bias[2 * H_ + ecol];
        bo  = bias[3 * H_ + ecol];
    }
    float creg[4] = {0.f, 0.f, 0.f, 0.f};

    const size_t aoff = (size_t)q * 512 + (size_t)(m0 + frow) * 8;
    const size_t stoff_e = (size_t)cb * 512 + (size_t)(m0 + (lane >> 2)) * 8
                         + (size_t)(lane & 3) * 2;

    if (!isL1) {
        // ------------- layer 0: superstep s computes t = s ------------------
        // Preload ALL step-invariant weight fragments into registers:
        // 26 k-chunks (2 x-part + 24 h-part) x 2 gate-pairs = 52 frags (208 VGPR).
        bf16x8 Bw0[26], Bw1[26];
        #pragma unroll
        for (int k = 0; k < 26; k++) {
            Bw0[k] = *(const bf16x8*)(Bp0 + k * 32);
            Bw1[k] = *(const bf16x8*)(Bp1 + k * 32);
        }
        for (int s = 0; s < T_; ++s) {
            f32x4 acc0 = {0.f, 0.f, 0.f, 0.f};
            f32x4 acc1 = {0.f, 0.f, 0.f, 0.f};
            {
                const unsigned short* xsp =
                    xsT + ((size_t)s * B_ + m0 + frow) * IN_ + kof;
                bf16x8 ax0 = *(const bf16x8*)(xsp);
                bf16x8 ax1 = *(const bf16x8*)(xsp + 32);
                acc0 = MFMA16(ax0, Bw0[0], acc0);
                acc1 = MFMA16(ax0, Bw1[0], acc1);
                acc0 = MFMA16(ax1, Bw0[1], acc0);
                acc1 = MFMA16(ax1, Bw1[1], acc1);
            }
            if (s > 0) {
                if (wave == 0) {   // scan all 96 producer flags directly
                    for (;;) {
                        int fa = AGENT_LD(&rep0[i1]);
                        int fb = AGENT_LD(&rep0[i2]);
                        if (__all(fa >= s && fb >= s)) break;
                        __builtin_amdgcn_s_sleep(1);
                    }
                }
                __syncthreads();
                const unsigned short* hr = h1ring + (size_t)(s - 1) * SLOT_ + aoff;
                // all 24 LLC loads in flight at once (96 VGPR)
                bf16x8 a[24];
                #pragma unroll
                for (int kj = 0; kj < 24; kj++)
                    a[kj] = *(const bf16x8*)(hr + kj * 2048);
                #pragma unroll
                for (int kj = 0; kj < 24; kj++) {
                    acc0 = MFMA16(a[kj], Bw0[kj + 2], acc0);
                    acc1 = MFMA16(a[kj], Bw1[kj + 2], acc1);
                }
            }
            f32x4 pacc0, pacc1;
            #pragma unroll
            for (int j = 0; j < 4; j++) {
                pacc0[j] = __shfl_xor(acc0[j], 8);
                pacc1[j] = __shfl_xor(acc1[j], 8);
            }
            if (lowhalf) {
                #pragma unroll
                for (int j = 0; j < 4; j++) {
                    float pi = acc0[j]  + bi;
                    float pf = pacc0[j] + bff;
                    float pg = acc1[j]  + bg;
                    float po = pacc1[j] + bo;
                    float cn = fast_sigm(pf) * creg[j] + fast_sigm(pi) * fast_tanh(pg);
                    float hn = fast_sigm(po) * fast_tanh(cn);
                    creg[j] = cn;
                    ldsb[wave][q * 4 + j][lane & 7] = f2bf(hn);
                }
            }
            unsigned v = ((const unsigned*)&ldsb[wave][0][0])[lane];
            st_llc_u32((unsigned*)(h1ring + (size_t)s * SLOT_ + stoff_e), v);
            asm volatile("s_waitcnt vmcnt(0)" ::: "memory");
            __syncthreads();   // all 4 waves' h stores drained
            if (wave == 0 && lane < 8)   // publish epoch s+1 to 8 replicas
                st_llc_u32((unsigned*)&f0[lane * 128 + cb], (unsigned)(s + 1));
        }
    } else {
        // ------------- layer 1: superstep s computes t = s - 1 --------------
        // Preload h1-part weights (48 frags, 192 VGPR); h2-part streamed
        // from warm L2 under the h1 MFMA chain.
        bf16x8 Bw0[24], Bw1[24];
        #pragma unroll
        for (int k = 0; k < 24; k++) {
            Bw0[k] = *(const bf16x8*)(Bp0 + k * 32);
            Bw1[k] = *(const bf16x8*)(Bp1 + k * 32);
        }
        for (int s = 1; s <= T_; ++s) {
            const int t = s - 1;
            if (wave == 0) {   // h1[t] ready when all f0 >= t+1 = s
                for (;;) {
                    int fa = AGENT_LD(&rep0[i1]);
                    int fb = AGENT_LD(&rep0[i2]);
                    if (__all(fa >= s && fb >= s)) break;
                    __builtin_amdgcn_s_sleep(1);
                }
            }
            if (wave == 1 && t > 0) {   // h2[t-1] ready when all f1 >= t
                for (;;) {
                    int fa = AGENT_LD(&rep1[i1]);
                    int fb = AGENT_LD(&rep1[i2]);
                    if (__all(fa >= t && fb >= t)) break;
                    __builtin_amdgcn_s_sleep(1);
                }
            }
            __syncthreads();
            f32x4 acc0 = {0.f, 0.f, 0.f, 0.f};
            f32x4 acc1 = {0.f, 0.f, 0.f, 0.f};
            const unsigned short* h1r = h1ring + (size_t)t * SLOT_ + aoff;
            if (t > 0) {
                const unsigned short* h2r = h2ring + (size_t)(t - 1) * SLOT_ + aoff;
                // issue ALL 48 LLC loads up front (192 VGPR in flight)
                bf16x8 a1[24];
                #pragma unroll
                for (int ki = 0; ki < 24; ki++)
                    a1[ki] = *(const bf16x8*)(h1r + ki * 2048);
                bf16x8 a2[24];
                #pragma unroll
                for (int ki = 0; ki < 24; ki++)
                    a2[ki] = *(const bf16x8*)(h2r + ki * 2048);
                // h1 half: B in registers, MFMAs start as soon as a1 lands
                #pragma unroll
                for (int ki = 0; ki < 24; ki++) {
                    acc0 = MFMA16(a1[ki], Bw0[ki], acc0);
                    acc1 = MFMA16(a1[ki], Bw1[ki], acc1);
                }
                // h2 half: B streamed from L2, latency hidden by h1 MFMA chain
                #pragma unroll
                for (int ki = 0; ki < 24; ki++) {
                    bf16x8 b0 = *(const bf16x8*)(Bp0 + (ki + 24) * 32);
                    bf16x8 b1 = *(const bf16x8*)(Bp1 + (ki + 24) * 32);
                    acc0 = MFMA16(a2[ki], b0, acc0);
                    acc1 = MFMA16(a2[ki], b1, acc1);
                }
            } else {
                bf16x8 a1[24];
                #pragma unroll
                for (int ki = 0; ki < 24; ki++)
                    a1[ki] = *(const bf16x8*)(h1r + ki * 2048);
                #pragma unroll
                for (int ki = 0; ki < 24; ki++) {
                    acc0 = MFMA16(a1[ki], Bw0[ki], acc0);
                    acc1 = MFMA16(a1[ki], Bw1[ki], acc1);
                }
            }
            f32x4 pacc0, pacc1;
            #pragma unroll
            for (int j = 0; j < 4; j++) {
                pacc0[j] = __shfl_xor(acc0[j], 8);
                pacc1[j] = __shfl_xor(acc1[j], 8);
            }
            if (lowhalf) {
                #pragma unroll
                for (int j = 0; j < 4; j++) {
                    int row = m0 + q * 4 + j;
                    float pi = acc0[j]  + bi;
                    float pf = pacc0[j] + bff;
                    float pg = acc1[j]  + bg;
                    float po = pacc1[j] + bo;
                    float cn = fast_sigm(pf) * creg[j] + fast_sigm(pi) * fast_tanh(pg);
                    float hn = fast_sigm(po) * fast_tanh(cn);
                    creg[j] = cn;
                    ldsb[wave][q * 4 + j][lane & 7] = f2bf(hn);
                    if (t == T_ - 1) hf32[(size_t)row * H_ + ecol] = hn;
                }
            }
            unsigned v = ((const unsigned*)&ldsb[wave][0][0])[lane];
            st_llc_u32((unsigned*)(h2ring + (size_t)t * SLOT_ + stoff_e), v);
            asm volatile("s_waitcnt vmcnt(0)" ::: "memory");
            __syncthreads();
            if (wave == 0 && lane < 8)
                st_llc_u32((unsigned*)&f1[lane * 128 + cb], (unsigned)s);
        }
        if (wg == NWG0 && tid == 0) st_llc_u32((unsigned*)done, 1u);
    }
}

// ---------------- head ----------------
__global__ __launch_bounds__(256) void head_kernel(
    const float* __restrict__ hlast,
    const float* __restrict__ W1, const float* __restrict__ b1,
    const float* __restrict__ W2, const float* __restrict__ b2,
    float* __restrict__ out)
{
    __shared__ float hs[H_];
    __shared__ float partial[4];
    int b = blockIdx.x;
    int tid = threadIdx.x;
    for (int j = tid; j < H_; j += 256) hs[j] = hlast[(size_t)b * H_ + j];
    __syncthreads();
    float z = 0.f;
    const float* w = W1 + (size_t)tid * H_;
    for (int j = 0; j < H_; j++) z += hs[j] * w[j];
    z += b1[tid];
    z = z / (1.0f + fabsf(z));
    float p = z * W2[tid];
    #pragma unroll
    for (int off = 32; off > 0; off >>= 1) p += __shfl_down(p, off, 64);
    if ((tid & 63) == 0) partial[tid >> 6] = p;
    __syncthreads();
    if (tid == 0) {
        float s = partial[0] + partial[1] + partial[2] + partial[3];
        out[b] = (s + b2[0]) * 70.0f;
    }
}

extern "C" void kernel_launch(void* const* d_in, const int* in_sizes, int n_in,
                              void* d_out, int out_size, void* d_ws, size_t ws_size,
                              hipStream_t stream) {
    const float* x    = (const float*)d_in[0];
    const float* Wih0 = (const float*)d_in[1];
    const float* Whh0 = (const float*)d_in[2];
    const float* bih0 = (const float*)d_in[3];
    const float* bhh0 = (const float*)d_in[4];
    const float* Wih1 = (const float*)d_in[5];
    const float* Whh1 = (const float*)d_in[6];
    const float* bih1 = (const float*)d_in[7];
    const float* bhh1 = (const float*)d_in[8];
    const float* W1   = (const float*)d_in[9];
    const float* b1   = (const float*)d_in[10];
    const float* W2   = (const float*)d_in[11];
    const float* b2   = (const float*)d_in[12];
    float* out = (float*)d_out;

    char* w = (char*)d_ws;
    int* ctrs = (int*)w;                          w += 65536;
    unsigned short* h1ring = (unsigned short*)w;  w += (size_t)T_ * SLOT_ * 2;
    unsigned short* h2ring = (unsigned short*)w;  w += (size_t)T_ * SLOT_ * 2;
    unsigned short* xsT    = (unsigned short*)w;  w += (size_t)B_ * T_ * IN_ * 2;
    unsigned short* W0cat  = (unsigned short*)w;  w += (size_t)G_ * K0_ * 2;
    unsigned short* W1cat  = (unsigned short*)w;  w += (size_t)G_ * K1_ * 2;
    float* bias0 = (float*)w;                     w += G_ * 4;
    float* bias1 = (float*)w;                     w += G_ * 4;
    float* hf32  = (float*)w;                     w += (size_t)B_ * H_ * 4;

    prep_kernel<<<1024, 256, 0, stream>>>(x, Wih0, Whh0, bih0, bhh0,
                                          Wih1, Whh1, bih1, bhh1,
                                          xsT, W0cat, W1cat, bias0, bias1, ctrs);
    lstm_persistent<<<NWGT, 256, 0, stream>>>(xsT, W0cat, W1cat, bias0, bias1,
                                              h1ring, h2ring, hf32, ctrs);
    head_kernel<<<B_, 256, 0, stream>>>(hf32, W1, b1, W2, b2, out);
}